// Round 2
// baseline (194.673 us; speedup 1.0000x reference)
//
#include <hip/hip_runtime.h>

#define N_NODES 100000
#define N_EDGES 1250000
#define FEATS 64

#define NPB    64                              // nodes per bucket (was 128)
#define NPB_SH 6
#define NBUCK ((N_NODES + NPB - 1) / NPB)      // 1563
#define CAP    1280                            // slots/bucket; mean 800, sd 28 -> +17 sigma
#define TILE   1024                            // edges per binning block (was 4096)
#define EPT    4                               // edges per thread
#define NTILES ((N_EDGES + TILE - 1) / TILE)   // 1221

typedef unsigned short ushort8 __attribute__((ext_vector_type(8)));

__device__ __forceinline__ float bf2f(unsigned short u) {
    return __uint_as_float(((unsigned int)u) << 16);
}
__device__ __forceinline__ unsigned short f2bf(float f) {
    unsigned int x = __float_as_uint(f);
    unsigned int lsb = (x >> 16) & 1u;
    x += 0x7fffu + lsb;                 // round-to-nearest-even
    return (unsigned short)(x >> 16);
}

// ---------------------------------------------------------------------------
// ws layout:
//   cursor [2048]            bucket sizes (memset 0; binA atomicAdd, relative)
//   pairs  int[1563*1280]    packed (src<<6 | dst&63), 8.0 MB
//   hb     ushort[6.4M]      bf16 h copy, 12.8 MB
// total ~20.8 MB (< proven 25.6 MB)
// ---------------------------------------------------------------------------

// Fused: (a) grid-stride pack h -> bf16, (b) bin edges into 1563 buckets by
// dst>>6 via LDS histogram + one global atomicAdd per (tile,bucket).
// Grid 1221 blocks (was 306): both phases were latency-bound at ~1.2 blk/CU.
__global__ __launch_bounds__(256) void binA_pack_kernel(
        const float* __restrict__ h,
        unsigned short* __restrict__ hb,
        const int* __restrict__ src,
        const int* __restrict__ dst,
        int* __restrict__ cursor,
        int* __restrict__ pairs) {
    // ---- pack prologue (independent of binning) ----
    const int PTOT = N_NODES * FEATS;           // 6.4M, %8 == 0
    for (int i = (blockIdx.x * 256 + threadIdx.x) * 8; i < PTOT;
         i += gridDim.x * 256 * 8) {
        float4 a = *(const float4*)(h + i);
        float4 c = *(const float4*)(h + i + 4);
        ushort8 u;
        u[0] = f2bf(a.x); u[1] = f2bf(a.y); u[2] = f2bf(a.z); u[3] = f2bf(a.w);
        u[4] = f2bf(c.x); u[5] = f2bf(c.y); u[6] = f2bf(c.z); u[7] = f2bf(c.w);
        *(ushort8*)(hb + i) = u;
    }

    // ---- binning ----
    __shared__ int hist[NBUCK];
    __shared__ int base[NBUCK];
    const int t  = threadIdx.x;
    const int e0 = blockIdx.x * TILE + t * EPT;
    const bool full = (blockIdx.x + 1) * TILE <= N_EDGES;

    for (int i = t; i < NBUCK; i += 256) hist[i] = 0;
    __syncthreads();

    int d[EPT], lr[EPT];
    if (full) {
        int4 v = *(const int4*)(dst + e0);
        d[0] = v.x; d[1] = v.y; d[2] = v.z; d[3] = v.w;
#pragma unroll
        for (int j = 0; j < EPT; ++j) lr[j] = atomicAdd(&hist[d[j] >> NPB_SH], 1);
    } else {
#pragma unroll
        for (int j = 0; j < EPT; ++j) {
            if (e0 + j < N_EDGES) {
                d[j]  = dst[e0 + j];
                lr[j] = atomicAdd(&hist[d[j] >> NPB_SH], 1);
            }
        }
    }
    __syncthreads();

    for (int i = t; i < NBUCK; i += 256)
        base[i] = hist[i] ? atomicAdd(&cursor[i], hist[i]) : 0;   // relative
    __syncthreads();

    if (full) {
        int4 v = *(const int4*)(src + e0);
        int s[EPT];
        s[0] = v.x; s[1] = v.y; s[2] = v.z; s[3] = v.w;
#pragma unroll
        for (int j = 0; j < EPT; ++j) {
            int bk  = d[j] >> NPB_SH;
            int rel = base[bk] + lr[j];
            if (rel < CAP)                       // overflow guard (never hits)
                pairs[(size_t)bk * CAP + rel] = (s[j] << NPB_SH) | (d[j] & (NPB - 1));
        }
    } else {
#pragma unroll
        for (int j = 0; j < EPT; ++j) {
            if (e0 + j < N_EDGES) {
                int bk  = d[j] >> NPB_SH;
                int rel = base[bk] + lr[j];
                if (rel < CAP)
                    pairs[(size_t)bk * CAP + rel] =
                        (src[e0 + j] << NPB_SH) | (d[j] & (NPB - 1));
            }
        }
    }
}

// ---------------------------------------------------------------------------
// One block per 64-node bucket (grid 1563, was 782 -- occupancy was
// grid-limited at 26%):
//   1. counting sort of the bucket's edges by dst&63 entirely in LDS
//   2. gather: 8-lane group per node, ushort8 (16B) bf16 row loads,
//      fp32 register accumulate (R10's proven shape)
//   3. linear+bias+relu with W rows in VGPRs
// ---------------------------------------------------------------------------
__global__ __launch_bounds__(256) void agg_kernel(
        const unsigned short* __restrict__ hb,
        const int* __restrict__ pairs,
        const int* __restrict__ cursor,
        const float* __restrict__ W,    // [o][k] row-major
        const float* __restrict__ bias,
        float* __restrict__ out) {
    __shared__ int   ssrc[CAP];          // 5 KB sorted src ids
    __shared__ int   lcnt[NPB];
    __shared__ int   loff[NPB + 1];
    __shared__ int   lcur[NPB];
    __shared__ float srow[4][8][FEATS];  // 8 KB

    const int tid  = threadIdx.x;
    const int lane = tid & 63;
    const int wv   = tid >> 6;
    const int g    = lane >> 3;          // group 0..7
    const int li   = lane & 7;
    const int fo   = li * 8;             // my 8 feats

    float wr[FEATS];
#pragma unroll
    for (int kk = 0; kk < 16; ++kk) {
        float4 w4 = *(const float4*)(W + (size_t)lane * FEATS + kk * 4);
        wr[kk * 4 + 0] = w4.x;
        wr[kk * 4 + 1] = w4.y;
        wr[kk * 4 + 2] = w4.z;
        wr[kk * 4 + 3] = w4.w;
    }
    const float bv = bias[lane];

    const int b = blockIdx.x;
    int size = cursor[b];
    if (size > CAP) size = CAP;
    const int* bp = pairs + (size_t)b * CAP;

    // -- counting sort by dst&63 --
    if (tid < NPB) lcnt[tid] = 0;
    __syncthreads();
    for (int i = tid; i < size; i += 256) atomicAdd(&lcnt[bp[i] & (NPB - 1)], 1);
    __syncthreads();
    if (tid < NPB) lcur[tid] = lcnt[tid];      // scan scratch
    __syncthreads();
    for (int off = 1; off < NPB; off <<= 1) {
        int y = 0;
        if (tid < NPB && tid >= off) y = lcur[tid - off];
        __syncthreads();
        if (tid < NPB) lcur[tid] += y;
        __syncthreads();
    }
    if (tid < NPB) loff[tid + 1] = lcur[tid];  // inclusive -> loff[1..64]
    if (tid == 0) loff[0] = 0;
    __syncthreads();
    if (tid < NPB) lcur[tid] = loff[tid];
    __syncthreads();
    for (int i = tid; i < size; i += 256) {
        int p = bp[i];
        int r = atomicAdd(&lcur[p & (NPB - 1)], 1);
        ssrc[r] = p >> NPB_SH;
    }
    __syncthreads();

    // -- gather + linear, 2 passes of 32 nodes (4 waves x 8 groups) --
#pragma unroll
    for (int pass = 0; pass < 2; ++pass) {
        const int ln  = pass * 32 + wv * 8 + g;
        const int beg = loff[ln];
        const int m   = loff[ln + 1] - beg;

        float acc0[8], acc1[8];
#pragma unroll
        for (int i = 0; i < 8; ++i) { acc0[i] = 0.f; acc1[i] = 0.f; }

        for (int base = 0; __any(base < m); base += 8) {
#pragma unroll
            for (int t = 0; t < 8; t += 2) {
                const int i0 = base + t, i1 = base + t + 1;
                int r0 = (i0 < m) ? ssrc[beg + i0] : 0;
                int r1 = (i1 < m) ? ssrc[beg + i1] : 0;
                if (i0 < m) {
                    ushort8 u = *(const ushort8*)(hb + (size_t)r0 * FEATS + fo);
#pragma unroll
                    for (int i = 0; i < 8; ++i) acc0[i] += bf2f(u[i]);
                }
                if (i1 < m) {
                    ushort8 u = *(const ushort8*)(hb + (size_t)r1 * FEATS + fo);
#pragma unroll
                    for (int i = 0; i < 8; ++i) acc1[i] += bf2f(u[i]);
                }
            }
        }
#pragma unroll
        for (int i = 0; i < 8; ++i) acc0[i] += acc1[i];

        *(float4*)&srow[wv][g][fo]     = make_float4(acc0[0], acc0[1], acc0[2], acc0[3]);
        *(float4*)&srow[wv][g][fo + 4] = make_float4(acc0[4], acc0[5], acc0[6], acc0[7]);
        // srow is wave-private: in-wave LDS ordering, no barrier needed

        const int n0 = b * NPB + pass * 32 + wv * 8;
#pragma unroll
        for (int gg = 0; gg < 8; ++gg) {
            const int nn = n0 + gg;
            if (nn >= N_NODES) break;
            const float4* ar = (const float4*)&srow[wv][gg][0];
            float o_acc = bv;
#pragma unroll
            for (int k4 = 0; k4 < 16; ++k4) {
                float4 r = ar[k4];               // b128 broadcast
                o_acc = fmaf(r.x, wr[k4 * 4 + 0], o_acc);
                o_acc = fmaf(r.y, wr[k4 * 4 + 1], o_acc);
                o_acc = fmaf(r.z, wr[k4 * 4 + 2], o_acc);
                o_acc = fmaf(r.w, wr[k4 * 4 + 3], o_acc);
            }
            out[(size_t)nn * FEATS + lane] = fmaxf(o_acc, 0.0f);
        }
    }
}

extern "C" void kernel_launch(void* const* d_in, const int* in_sizes, int n_in,
                              void* d_out, int out_size, void* d_ws, size_t ws_size,
                              hipStream_t stream) {
    const float* h   = (const float*)d_in[0];
    const int*   src = (const int*)d_in[1];
    const int*   dst = (const int*)d_in[2];
    const float* W   = (const float*)d_in[3];
    const float* b   = (const float*)d_in[4];
    float* out = (float*)d_out;

    int* cursor = (int*)d_ws;                          // 2048 ints
    int* pairs  = cursor + 2048;                       // 1563*1280 = 2.00M ints
    unsigned short* hb = (unsigned short*)(pairs + (size_t)NBUCK * CAP);  // 6.4M

    hipMemsetAsync(cursor, 0, 2048 * sizeof(int), stream);
    binA_pack_kernel<<<NTILES, 256, 0, stream>>>(h, hb, src, dst, cursor, pairs);
    agg_kernel<<<NBUCK, 256, 0, stream>>>(hb, pairs, cursor, W, b, out);
}

// Round 3
// 194.424 us; speedup vs baseline: 1.0013x; 1.0013x over previous
//
#include <hip/hip_runtime.h>

#define N_NODES 100000
#define N_EDGES 1250000
#define FEATS 64

#define NPB   128                              // nodes per bucket (round-0 proven)
#define NBUCK ((N_NODES + NPB - 1) / NPB)      // 782
#define CAP   2304                             // slots/bucket; mean 1600, sd 40 -> +17 sigma
#define TILE  4096
#define NTILES ((N_EDGES + TILE - 1) / TILE)   // 306

typedef unsigned short ushort8 __attribute__((ext_vector_type(8)));

__device__ __forceinline__ float bf2f(unsigned short u) {
    return __uint_as_float(((unsigned int)u) << 16);
}
__device__ __forceinline__ unsigned short f2bf(float f) {
    unsigned int x = __float_as_uint(f);
    unsigned int lsb = (x >> 16) & 1u;
    x += 0x7fffu + lsb;                 // round-to-nearest-even
    return (unsigned short)(x >> 16);
}

// ---------------------------------------------------------------------------
// ws layout (identical to round-0 proven):
//   cursor [1024]            bucket sizes (memset 0; binA atomicAdd, relative)
//   pairs  int[782*2304]     packed (src<<7 | dst&127), 7.2 MB
//   hb     ushort[6.4M]      bf16 h copy, 12.8 MB
// ---------------------------------------------------------------------------

// Fused: (a) grid-stride pack h -> bf16, (b) bin edges into 782 buckets.
// NEW: tile-local counting sort in LDS so the pairs writes are bucket-runs
// (~5 contiguous edges) instead of 1.25M isolated 4-B scatters -- cuts the
// write-allocate line traffic ~5x (theory: that RFO traffic WAS binA's cost).
__global__ __launch_bounds__(256) void binA_pack_kernel(
        const float* __restrict__ h,
        unsigned short* __restrict__ hb,
        const int* __restrict__ src,
        const int* __restrict__ dst,
        int* __restrict__ cursor,
        int* __restrict__ pairs) {
    // ---- pack prologue (independent of binning) ----
    const int PTOT = N_NODES * FEATS;           // 6.4M, %8 == 0
    for (int i = (blockIdx.x * 256 + threadIdx.x) * 8; i < PTOT;
         i += gridDim.x * 256 * 8) {
        float4 a = *(const float4*)(h + i);
        float4 c = *(const float4*)(h + i + 4);
        ushort8 u;
        u[0] = f2bf(a.x); u[1] = f2bf(a.y); u[2] = f2bf(a.z); u[3] = f2bf(a.w);
        u[4] = f2bf(c.x); u[5] = f2bf(c.y); u[6] = f2bf(c.z); u[7] = f2bf(c.w);
        *(ushort8*)(hb + i) = u;
    }

    // ---- binning with LDS staging ----
    __shared__ int hist[NBUCK];                 // per-tile bucket counts
    __shared__ int scn[NBUCK];                  // inclusive scan of hist
    __shared__ int gbase[NBUCK];                // global base from cursor
    __shared__ int stv[TILE];                   // staged packed values (16 KB)
    __shared__ unsigned short stb[TILE];        // staged bucket ids (8 KB)

    const int t     = threadIdx.x;
    const int tile0 = blockIdx.x * TILE;
    const int tsize = (N_EDGES - tile0 < TILE) ? (N_EDGES - tile0) : TILE;
    const bool full = (tsize == TILE);
    const int e0 = tile0 + t * 16;

    for (int i = t; i < NBUCK; i += 256) hist[i] = 0;
    __syncthreads();

    int d[16], lr[16];
    if (full) {
#pragma unroll
        for (int q = 0; q < 4; ++q) {
            int4 v = *(const int4*)(dst + e0 + q * 4);
            d[q * 4 + 0] = v.x; d[q * 4 + 1] = v.y;
            d[q * 4 + 2] = v.z; d[q * 4 + 3] = v.w;
        }
#pragma unroll
        for (int j = 0; j < 16; ++j) lr[j] = atomicAdd(&hist[d[j] >> 7], 1);
    } else {
#pragma unroll
        for (int j = 0; j < 16; ++j) {
            if (e0 + j < N_EDGES) {
                d[j]  = dst[e0 + j];
                lr[j] = atomicAdd(&hist[d[j] >> 7], 1);
            }
        }
    }
    __syncthreads();

    // inclusive Hillis-Steele scan of hist -> scn (in place, read/barrier/add)
    for (int i = t; i < NBUCK; i += 256) scn[i] = hist[i];
    __syncthreads();
    for (int off = 1; off < NBUCK; off <<= 1) {
        int y[4];
        int c = 0;
        for (int i = t; i < NBUCK; i += 256) y[c++] = (i >= off) ? scn[i - off] : 0;
        __syncthreads();
        c = 0;
        for (int i = t; i < NBUCK; i += 256) scn[i] += y[c++];
        __syncthreads();
    }

    // global cursor reservation (one atomic per non-empty bucket) +
    // stage the tile sorted by bucket (pos = exclusive_scan[bk] + rank)
    for (int i = t; i < NBUCK; i += 256)
        gbase[i] = hist[i] ? atomicAdd(&cursor[i], hist[i]) : 0;

    if (full) {
        int s[16];
#pragma unroll
        for (int q = 0; q < 4; ++q) {
            int4 v = *(const int4*)(src + e0 + q * 4);
            s[q * 4 + 0] = v.x; s[q * 4 + 1] = v.y;
            s[q * 4 + 2] = v.z; s[q * 4 + 3] = v.w;
        }
#pragma unroll
        for (int j = 0; j < 16; ++j) {
            int bk  = d[j] >> 7;
            int pos = scn[bk] - hist[bk] + lr[j];
            stv[pos] = (s[j] << 7) | (d[j] & (NPB - 1));
            stb[pos] = (unsigned short)bk;
        }
    } else {
#pragma unroll
        for (int j = 0; j < 16; ++j) {
            if (e0 + j < N_EDGES) {
                int bk  = d[j] >> 7;
                int pos = scn[bk] - hist[bk] + lr[j];
                stv[pos] = (src[e0 + j] << 7) | (d[j] & (NPB - 1));
                stb[pos] = (unsigned short)bk;
            }
        }
    }
    __syncthreads();

    // coalesced run-writes: consecutive i within a bucket-run -> consecutive
    // global addresses
    for (int i = t; i < tsize; i += 256) {
        int bk  = stb[i];
        int rel = gbase[bk] + (i - (scn[bk] - hist[bk]));
        if (rel < CAP)                           // overflow guard (never hits)
            pairs[(size_t)bk * CAP + rel] = stv[i];
    }
}

// ---------------------------------------------------------------------------
// One block per 128-node bucket:
//   1. counting sort of the bucket's edges by dst&127 in LDS
//   2. NEW: degree-rank the 128 nodes; concurrent group-slots get adjacent
//      ranks so the __any() loop bound ~= the octet mean, not the max
//      (cuts ~1.9x slot inflation to ~1.1x)
//   3. gather: 8-lane group per node, ushort8 bf16 rows, 4 accum chains
//   4. linear+bias+relu (unchanged shape; out row permuted via slotNode)
// ---------------------------------------------------------------------------
__global__ __launch_bounds__(256) void agg_kernel(
        const unsigned short* __restrict__ hb,
        const int* __restrict__ pairs,
        const int* __restrict__ cursor,
        const float* __restrict__ W,    // [o][k] row-major
        const float* __restrict__ bias,
        float* __restrict__ out) {
    __shared__ int   ssrc[CAP];          // 9.2 KB sorted src ids
    __shared__ int   lcnt[NPB];
    __shared__ int   loff[NPB + 1];
    __shared__ int   lcur[NPB];
    __shared__ int   slotNode[NPB];      // degree-rank -> node
    __shared__ float srow[4][8][FEATS];  // 8 KB

    const int tid  = threadIdx.x;
    const int lane = tid & 63;
    const int wv   = tid >> 6;
    const int g    = lane >> 3;          // group 0..7
    const int li   = lane & 7;
    const int fo   = li * 8;             // my 8 feats

    float wr[FEATS];
#pragma unroll
    for (int kk = 0; kk < 16; ++kk) {
        float4 w4 = *(const float4*)(W + (size_t)lane * FEATS + kk * 4);
        wr[kk * 4 + 0] = w4.x;
        wr[kk * 4 + 1] = w4.y;
        wr[kk * 4 + 2] = w4.z;
        wr[kk * 4 + 3] = w4.w;
    }
    const float bv = bias[lane];

    const int b = blockIdx.x;
    int size = cursor[b];
    if (size > CAP) size = CAP;
    const int* bp = pairs + (size_t)b * CAP;

    // -- counting sort by dst&127 --
    if (tid < NPB) lcnt[tid] = 0;
    __syncthreads();
    for (int i = tid; i < size; i += 256) atomicAdd(&lcnt[bp[i] & (NPB - 1)], 1);
    __syncthreads();
    if (tid < NPB) lcur[tid] = lcnt[tid];      // scan scratch
    __syncthreads();
    for (int off = 1; off < NPB; off <<= 1) {
        int y = 0;
        if (tid < NPB && tid >= off) y = lcur[tid - off];
        __syncthreads();
        if (tid < NPB) lcur[tid] += y;
        __syncthreads();
    }
    if (tid < NPB) loff[tid + 1] = lcur[tid];  // inclusive -> loff[1..128]
    if (tid == 0) loff[0] = 0;
    __syncthreads();
    if (tid < NPB) lcur[tid] = loff[tid];
    __syncthreads();
    for (int i = tid; i < size; i += 256) {
        int p = bp[i];
        int r = atomicAdd(&lcur[p & (NPB - 1)], 1);
        ssrc[r] = p >> 7;
    }

    // -- degree ranking (descending; ties by index) --
    if (tid < NPB) {
        const int cnt = lcnt[tid];
        int rank = 0;
        for (int j = 0; j < NPB; ++j) {
            int cj = lcnt[j];
            rank += (cj > cnt) || (cj == cnt && j < tid);
        }
        slotNode[rank] = tid;
    }
    __syncthreads();

    // -- gather + linear, 4 passes of 32 slots (4 waves x 8 groups) --
#pragma unroll
    for (int pass = 0; pass < 4; ++pass) {
        const int slot = pass * 32 + wv * 8 + g;
        const int ln   = slotNode[slot];
        const int beg  = loff[ln];
        const int m    = loff[ln + 1] - beg;

        float acc0[8], acc1[8], acc2[8], acc3[8];
#pragma unroll
        for (int i = 0; i < 8; ++i) {
            acc0[i] = 0.f; acc1[i] = 0.f; acc2[i] = 0.f; acc3[i] = 0.f;
        }

        for (int bb = 0; __any(bb < m); bb += 8) {
            const int i0 = bb + 0, i1 = bb + 1, i2 = bb + 2, i3 = bb + 3;
            const int i4 = bb + 4, i5 = bb + 5, i6 = bb + 6, i7 = bb + 7;
            int r0 = (i0 < m) ? ssrc[beg + i0] : 0;
            int r1 = (i1 < m) ? ssrc[beg + i1] : 0;
            int r2 = (i2 < m) ? ssrc[beg + i2] : 0;
            int r3 = (i3 < m) ? ssrc[beg + i3] : 0;
            int r4 = (i4 < m) ? ssrc[beg + i4] : 0;
            int r5 = (i5 < m) ? ssrc[beg + i5] : 0;
            int r6 = (i6 < m) ? ssrc[beg + i6] : 0;
            int r7 = (i7 < m) ? ssrc[beg + i7] : 0;
            if (i0 < m) {
                ushort8 u = *(const ushort8*)(hb + (size_t)r0 * FEATS + fo);
#pragma unroll
                for (int i = 0; i < 8; ++i) acc0[i] += bf2f(u[i]);
            }
            if (i1 < m) {
                ushort8 u = *(const ushort8*)(hb + (size_t)r1 * FEATS + fo);
#pragma unroll
                for (int i = 0; i < 8; ++i) acc1[i] += bf2f(u[i]);
            }
            if (i2 < m) {
                ushort8 u = *(const ushort8*)(hb + (size_t)r2 * FEATS + fo);
#pragma unroll
                for (int i = 0; i < 8; ++i) acc2[i] += bf2f(u[i]);
            }
            if (i3 < m) {
                ushort8 u = *(const ushort8*)(hb + (size_t)r3 * FEATS + fo);
#pragma unroll
                for (int i = 0; i < 8; ++i) acc3[i] += bf2f(u[i]);
            }
            if (i4 < m) {
                ushort8 u = *(const ushort8*)(hb + (size_t)r4 * FEATS + fo);
#pragma unroll
                for (int i = 0; i < 8; ++i) acc0[i] += bf2f(u[i]);
            }
            if (i5 < m) {
                ushort8 u = *(const ushort8*)(hb + (size_t)r5 * FEATS + fo);
#pragma unroll
                for (int i = 0; i < 8; ++i) acc1[i] += bf2f(u[i]);
            }
            if (i6 < m) {
                ushort8 u = *(const ushort8*)(hb + (size_t)r6 * FEATS + fo);
#pragma unroll
                for (int i = 0; i < 8; ++i) acc2[i] += bf2f(u[i]);
            }
            if (i7 < m) {
                ushort8 u = *(const ushort8*)(hb + (size_t)r7 * FEATS + fo);
#pragma unroll
                for (int i = 0; i < 8; ++i) acc3[i] += bf2f(u[i]);
            }
        }
#pragma unroll
        for (int i = 0; i < 8; ++i) acc0[i] += acc1[i] + (acc2[i] + acc3[i]);

        *(float4*)&srow[wv][g][fo]     = make_float4(acc0[0], acc0[1], acc0[2], acc0[3]);
        *(float4*)&srow[wv][g][fo + 4] = make_float4(acc0[4], acc0[5], acc0[6], acc0[7]);
        // srow is wave-private: in-wave LDS ordering, no barrier needed

        const int slotbase = pass * 32 + wv * 8;
#pragma unroll
        for (int gg = 0; gg < 8; ++gg) {
            const int nn = b * NPB + slotNode[slotbase + gg];
            if (nn < N_NODES) {
                const float4* ar = (const float4*)&srow[wv][gg][0];
                float o_acc = bv;
#pragma unroll
                for (int k4 = 0; k4 < 16; ++k4) {
                    float4 r = ar[k4];               // b128 broadcast
                    o_acc = fmaf(r.x, wr[k4 * 4 + 0], o_acc);
                    o_acc = fmaf(r.y, wr[k4 * 4 + 1], o_acc);
                    o_acc = fmaf(r.z, wr[k4 * 4 + 2], o_acc);
                    o_acc = fmaf(r.w, wr[k4 * 4 + 3], o_acc);
                }
                out[(size_t)nn * FEATS + lane] = fmaxf(o_acc, 0.0f);
            }
        }
    }
}

extern "C" void kernel_launch(void* const* d_in, const int* in_sizes, int n_in,
                              void* d_out, int out_size, void* d_ws, size_t ws_size,
                              hipStream_t stream) {
    const float* h   = (const float*)d_in[0];
    const int*   src = (const int*)d_in[1];
    const int*   dst = (const int*)d_in[2];
    const float* W   = (const float*)d_in[3];
    const float* b   = (const float*)d_in[4];
    float* out = (float*)d_out;

    int* cursor = (int*)d_ws;                          // 1024 ints
    int* pairs  = cursor + 1024;                       // 782*2304 = 1.80M ints
    unsigned short* hb = (unsigned short*)(pairs + (size_t)NBUCK * CAP);  // 6.4M

    hipMemsetAsync(cursor, 0, 1024 * sizeof(int), stream);
    binA_pack_kernel<<<NTILES, 256, 0, stream>>>(h, hb, src, dst, cursor, pairs);
    agg_kernel<<<NBUCK, 256, 0, stream>>>(hb, pairs, cursor, W, b, out);
}